// Round 13
// baseline (608.517 us; speedup 1.0000x reference)
//
#include <hip/hip_runtime.h>

typedef unsigned short u16;
typedef __attribute__((ext_vector_type(8))) short bf8v;   // 8 bf16 = 4 VGPRs
typedef __attribute__((ext_vector_type(4))) float f4v;

#define DEV static __device__ __forceinline__

DEV float bf2f(u16 u){ unsigned x = ((unsigned)u) << 16; float f; __builtin_memcpy(&f, &x, 4); return f; }
DEV u16 f2bf(float f){ unsigned x; __builtin_memcpy(&x, &f, 4); x += 0x7fff + ((x >> 16) & 1); return (u16)(x >> 16); }

DEV void async16(const void* g, void* l){
  __builtin_amdgcn_global_load_lds((const __attribute__((address_space(1))) unsigned*)g,
                                   (__attribute__((address_space(3))) unsigned*)l, 16, 0, 0);
}

DEV void vwait8(){ asm volatile("s_waitcnt vmcnt(8)" ::: "memory"); }
DEV void vwait6(){ asm volatile("s_waitcnt vmcnt(6)" ::: "memory"); }
DEV void vwait0(){ asm volatile("s_waitcnt vmcnt(0)" ::: "memory"); }
DEV void vw(int n){
  switch(n){
    case 8: asm volatile("s_waitcnt vmcnt(8)" ::: "memory"); break;
    case 4: asm volatile("s_waitcnt vmcnt(4)" ::: "memory"); break;
    case 2: asm volatile("s_waitcnt vmcnt(2)" ::: "memory"); break;
    default: asm volatile("s_waitcnt vmcnt(0)" ::: "memory"); break;
  }
}
DEV void bar(){ asm volatile("s_barrier" ::: "memory"); }

// ---------------------------------------------------------------------------
// fp32 -> bf16 conversion, 4 elements/thread (kept for tier-2 / fallback).
// ---------------------------------------------------------------------------
__global__ __launch_bounds__(256) void f2b_k(const float* __restrict__ src,
                                             u16* __restrict__ dst)
{
  const long i = ((long)blockIdx.x * 256 + threadIdx.x) * 4;
  const float4 v = *(const float4*)(src + i);
  ushort4 o;
  o.x = f2bf(v.x); o.y = f2bf(v.y); o.z = f2bf(v.z); o.w = f2bf(v.w);
  *(ushort4*)(dst + i) = o;
}

// ---------------------------------------------------------------------------
// f2ball_k: ALL fp32->bf16 conversions in ONE dispatch (round-13: boundary
// reduction — measured ~10us/boundary launch gap is the largest addressable
// pool). Sections by blockIdx.x:
//   [0,8192)      x  -> xb      (2E elems)
//   [8192,20480)  Wq/Wk/Wv -> wqkv [6144,2048]
//   [20480,24576) Wo -> wob     (only reached when grid=24576, ws>=12E tier)
// Math identical to old f2b/f2b3 -> bit-identical outputs.
// ---------------------------------------------------------------------------
__global__ __launch_bounds__(256) void f2ball_k(const float* __restrict__ x,
                                                const float* __restrict__ wq,
                                                const float* __restrict__ wk,
                                                const float* __restrict__ wv,
                                                const float* __restrict__ wo,
                                                u16* __restrict__ xb,
                                                u16* __restrict__ wqkv,
                                                u16* __restrict__ wob)
{
  const int bx = blockIdx.x;
  const int tid = threadIdx.x;
  const float* s;
  u16* d;
  long soff, doff;
  if (bx < 8192) {
    s = x; d = xb;
    soff = doff = (long)bx * 1024 + tid * 4;
  } else if (bx < 20480) {
    const int b2 = bx - 8192;                    // 0..12287
    s = b2 < 4096 ? wq : (b2 < 8192 ? wk : wv);
    d = wqkv;
    soff = (long)(b2 & 4095) * 1024 + tid * 4;
    doff = (long)b2 * 1024 + tid * 4;
  } else {
    const int b3 = bx - 20480;                   // 0..4095
    s = wo; d = wob;
    soff = doff = (long)b3 * 1024 + tid * 4;
  }
  const float4 v = *(const float4*)(s + soff);
  ushort4 o;
  o.x = f2bf(v.x); o.y = f2bf(v.y); o.z = f2bf(v.z); o.w = f2bf(v.w);
  *(ushort4*)(d + doff) = o;
}

// ---------------------------------------------------------------------------
// gemmq (round-7/9/12 proven, FROZEN): 256x256 tile, BK=64, 8 waves, dbuf
// 128 KB, fine ring, counted vmcnt per phase. 96 us @ 256-block grids,
// MfmaUtil ~28%. Clock tripwire: ~190us => degraded-clock session.
// ---------------------------------------------------------------------------
constexpr int KDIM = 2048;

__global__ __launch_bounds__(512, 2) void gemmq(const u16* __restrict__ A,
                                                const u16* __restrict__ B,
                                                u16* __restrict__ C0,
                                                u16* __restrict__ C1,
                                                u16* __restrict__ C2,
                                                float* __restrict__ Cf, int mode)
{
  __shared__ __align__(16) u16 Asm[2][16384];   // 64 KB
  __shared__ __align__(16) u16 Bsm[2][16384];   // 64 KB

  const int tid = threadIdx.x;
  const int w = tid >> 6, lane = tid & 63;
  const int ln = lane & 15, quad = lane >> 4;
  const int wr = w >> 2, wc = w & 3;           // 2 x 4 wave grid

  const int gx = gridDim.x;
  const int nwg = gx * gridDim.y;
  const int wg = blockIdx.y * gx + blockIdx.x;
  const int swz = (wg & 7) * (nwg >> 3) + (wg >> 3);
  const int bx = swz % gx, by = swz / gx;
  const long m0 = (long)by << 8, n0 = (long)bx << 8;

  f4v acc[8][4] = {};

  const int q = w >> 1;                        // 0..3
  const int colb = (w & 1) * 32 + quad * 8;    // k elems within BK
  long gArow[4], gBrow[4];
  {
    const int Ab4[4] = {0, 8, 4, 12};
    const int Bb4[4] = {0, 8, 2, 10};
#pragma unroll
    for (int r = 0; r < 4; ++r) {
      gArow[r] = (long)((Ab4[r] + q) * 16 + ln) * KDIM;
      gBrow[r] = (long)((Bb4[r] + (q & 1) + (q >> 1) * 4) * 16 + ln) * KDIM;
    }
  }
  const u16* gA = A + m0 * KDIM + colb;
  const u16* gB = B + n0 * KDIM + colb;

#define STAGE_A(sl, r, kt) async16(gA + gArow[r] + (kt), (char*)Asm + (sl)*32768 + (r)*8192 + w*1024)
#define STAGE_B(sl, r, kt) async16(gB + gBrow[r] + (kt), (char*)Bsm + (sl)*32768 + (r)*8192 + w*1024)

  STAGE_A(0,0,0);  STAGE_A(0,1,0);    // Al_0
  STAGE_B(0,0,0);  STAGE_B(0,1,0);    // Bl_0
  STAGE_B(0,2,0);  STAGE_B(0,3,0);    // Bh_0
  STAGE_A(0,2,0);  STAGE_A(0,3,0);    // Ah_0
  STAGE_A(1,0,64); STAGE_A(1,1,64);   // Al_1
  STAGE_B(1,0,64); STAGE_B(1,1,64);   // Bl_1
  vwait8();
  bar();

  const int nt = KDIM / 64;   // 32
  for (int t = 0; t < nt; ++t) {
    const int cs = t & 1;
    const u16* Ab = Asm[cs];
    const u16* Bb = Bsm[cs];
    int w1 = 8, w2 = 8, w3 = 8, w4 = 8;
    if (t == nt - 2) { w4 = 4; }
    else if (t == nt - 1) { w1 = 2; w2 = 0; w3 = 0; w4 = 0; }
    const long kn1 = (long)(t + 1) * 64;
    const long kn2 = (long)(t + 2) * 64;

    bf8v aL[4][2], aH[4][2], bL[2][2], bH[2][2];

    // ---- phase 1 ----
#pragma unroll
    for (int i = 0; i < 4; ++i) {
      const int ib = (i + wr * 4) * 2;
      aL[i][0] = *(const bf8v*)&Ab[((ib + 0) * 64 + lane) * 8];
      aL[i][1] = *(const bf8v*)&Ab[((ib + 1) * 64 + lane) * 8];
    }
#pragma unroll
    for (int j = 0; j < 2; ++j) {
      const int jb = (j + wc * 2) * 2;
      bL[j][0] = *(const bf8v*)&Bb[((jb + 0) * 64 + lane) * 8];
      bL[j][1] = *(const bf8v*)&Bb[((jb + 1) * 64 + lane) * 8];
    }
    if (t + 1 < nt) { STAGE_B(cs ^ 1, 2, kn1); STAGE_B(cs ^ 1, 3, kn1); }
    vw(w1); bar();
    __builtin_amdgcn_s_setprio(1);
#pragma unroll
    for (int i = 0; i < 4; ++i)
#pragma unroll
      for (int j = 0; j < 2; ++j) {
        acc[i][j] = __builtin_amdgcn_mfma_f32_16x16x32_bf16(aL[i][0], bL[j][0], acc[i][j], 0, 0, 0);
        acc[i][j] = __builtin_amdgcn_mfma_f32_16x16x32_bf16(aL[i][1], bL[j][1], acc[i][j], 0, 0, 0);
      }
    __builtin_amdgcn_s_setprio(0);

    // ---- phase 2 ----
#pragma unroll
    for (int j = 0; j < 2; ++j) {
      const int jb = ((j & 1) + 8 + wc * 2) * 2;
      bH[j][0] = *(const bf8v*)&Bb[((jb + 0) * 64 + lane) * 8];
      bH[j][1] = *(const bf8v*)&Bb[((jb + 1) * 64 + lane) * 8];
    }
    if (t + 1 < nt) { STAGE_A(cs ^ 1, 2, kn1); STAGE_A(cs ^ 1, 3, kn1); }
    vw(w2); bar();
    __builtin_amdgcn_s_setprio(1);
#pragma unroll
    for (int i = 0; i < 4; ++i)
#pragma unroll
      for (int j = 0; j < 2; ++j) {
        acc[i][2 + j] = __builtin_amdgcn_mfma_f32_16x16x32_bf16(aL[i][0], bH[j][0], acc[i][2 + j], 0, 0, 0);
        acc[i][2 + j] = __builtin_amdgcn_mfma_f32_16x16x32_bf16(aL[i][1], bH[j][1], acc[i][2 + j], 0, 0, 0);
      }
    __builtin_amdgcn_s_setprio(0);

    // ---- phase 3 ----
#pragma unroll
    for (int i = 0; i < 4; ++i) {
      const int ib = (i + 8 + wr * 4) * 2;
      aH[i][0] = *(const bf8v*)&Ab[((ib + 0) * 64 + lane) * 8];
      aH[i][1] = *(const bf8v*)&Ab[((ib + 1) * 64 + lane) * 8];
    }
    if (t + 2 < nt) { STAGE_A(cs, 0, kn2); STAGE_A(cs, 1, kn2); }
    vw(w3); bar();
    __builtin_amdgcn_s_setprio(1);
#pragma unroll
    for (int i = 0; i < 4; ++i)
#pragma unroll
      for (int j = 0; j < 2; ++j) {
        acc[4 + i][j] = __builtin_amdgcn_mfma_f32_16x16x32_bf16(aH[i][0], bL[j][0], acc[4 + i][j], 0, 0, 0);
        acc[4 + i][j] = __builtin_amdgcn_mfma_f32_16x16x32_bf16(aH[i][1], bL[j][1], acc[4 + i][j], 0, 0, 0);
      }
    __builtin_amdgcn_s_setprio(0);

    // ---- phase 4 ----
    if (t + 2 < nt) { STAGE_B(cs, 0, kn2); STAGE_B(cs, 1, kn2); }
    vw(w4); bar();
    __builtin_amdgcn_s_setprio(1);
#pragma unroll
    for (int i = 0; i < 4; ++i)
#pragma unroll
      for (int j = 0; j < 2; ++j) {
        acc[4 + i][2 + j] = __builtin_amdgcn_mfma_f32_16x16x32_bf16(aH[i][0], bH[j][0], acc[4 + i][2 + j], 0, 0, 0);
        acc[4 + i][2 + j] = __builtin_amdgcn_mfma_f32_16x16x32_bf16(aH[i][1], bH[j][1], acc[4 + i][2 + j], 0, 0, 0);
      }
    __builtin_amdgcn_s_setprio(0);
  }
#undef STAGE_A
#undef STAGE_B

#pragma unroll
  for (int i = 0; i < 8; i++) {
    const long mrow = m0 + wr * 128 + i * 16 + quad * 4;
#pragma unroll
    for (int j = 0; j < 4; j++) {
      const long ncol = n0 + wc * 64 + j * 16 + ln;
#pragma unroll
      for (int r = 0; r < 4; r++) {
        const float fv = acc[i][j][r];
        const long m = mrow + r;
        if (mode == 0) {
          C0[m * 2048 + ncol] = f2bf(fv);
        } else if (mode == 2) {
          Cf[m * 2048 + ncol] = fv;
        } else if (mode == 1) {
          const long s = m & 2047, bb = m >> 11;
          const long hh = ncol >> 7, dc = ncol & 127;
          C0[((bb * 16 + hh) * 128 + dc) * 2048 + s] = f2bf(fv);
        } else {
          const int sec = (int)(n0 >> 11);
          const long nc = ncol & 2047;
          if (sec == 0)      C0[m * 2048 + nc] = f2bf(fv);
          else if (sec == 1) C1[m * 2048 + nc] = f2bf(fv);
          else {
            const long s = m & 2047, bb = m >> 11;
            const long hh = nc >> 7, dc = nc & 127;
            C2[((bb * 16 + hh) * 128 + dc) * 2048 + s] = f2bf(fv);
          }
        }
      }
    }
  }
}

// ---------------------------------------------------------------------------
// GEMM v5 (round-4 proven, UNCHANGED): 128x256 tile, 3-slot ring, fine
// interleave, one counted vmcnt(6)/tile. nofs = N-column offset.
// ---------------------------------------------------------------------------
__global__ __launch_bounds__(512, 2) void gemm256(const u16* __restrict__ A,
                                                  const u16* __restrict__ B,
                                                  u16* __restrict__ C0,
                                                  u16* __restrict__ C1,
                                                  u16* __restrict__ C2,
                                                  float* __restrict__ Cf, int mode,
                                                  int nofs)
{
  __shared__ __align__(16) u16 Asm[3][8192];    // 3 x 16 KB
  __shared__ __align__(16) u16 Bsm[3][16384];   // 3 x 32 KB

  const int tid = threadIdx.x;
  const int w = tid >> 6, lane = tid & 63;
  const int ln = lane & 15, quad = lane >> 4;
  const int wr = w >> 2, wc = w & 3;

  const int gx = gridDim.x;
  const int nwg = gx * gridDim.y;
  const int wg = blockIdx.y * gx + blockIdx.x;
  const int swz = (wg & 7) * (nwg >> 3) + (wg >> 3);
  const int bx = swz % gx, by = swz / gx;
  const long m0 = (long)by << 7, n0 = ((long)bx << 8) + nofs;

  f4v acc[4][4] = {};

  const u16* pA  = A + (m0 + w * 16 + ln) * (long)KDIM + quad * 8;
  const u16* pB0 = B + (n0 + w * 16 + ln) * (long)KDIM + quad * 8;
  const u16* pB1 = B + (n0 + (8 + w) * 16 + ln) * (long)KDIM + quad * 8;
  char* ldsA = (char*)Asm + (long)tid * 16;
  char* ldsB = (char*)Bsm + (long)tid * 16;

#define STG(sl, ks, kt) do{                                                     \
    async16(pA  + (kt) + (ks) * 32, ldsA + (sl) * 16384 + (ks) * 8192);         \
    async16(pB0 + (kt) + (ks) * 32, ldsB + (sl) * 32768 + (ks) * 16384);        \
    async16(pB1 + (kt) + (ks) * 32, ldsB + (sl) * 32768 + (ks) * 16384 + 8192); \
  }while(0)

  STG(0, 0, 0);  STG(0, 1, 0);
  STG(1, 0, 64); STG(1, 1, 64);
  vwait6();
  bar();

  int s0 = 0, s1 = 1, s2 = 2;
  const int nt = KDIM / 64;           // 32
  for (int t = 0; t < nt; ++t) {
    const u16* Ab = Asm[s0];
    const u16* Bb = Bsm[s0];
    const bool st = (t + 2 < nt);
    const long kt2 = (long)(t + 2) * 64;

    bf8v a0[4], b0[4];
#pragma unroll
    for (int i = 0; i < 4; ++i) a0[i] = *(const bf8v*)&Ab[((wr * 4 + i) * 64 + lane) * 8];
#pragma unroll
    for (int j = 0; j < 4; ++j) b0[j] = *(const bf8v*)&Bb[((wc * 4 + j) * 64 + lane) * 8];
    if (st) STG(s2, 0, kt2);
    bar();
    __builtin_amdgcn_s_setprio(1);
#pragma unroll
    for (int i = 0; i < 4; ++i)
#pragma unroll
      for (int j = 0; j < 4; ++j)
        acc[i][j] = __builtin_amdgcn_mfma_f32_16x16x32_bf16(a0[i], b0[j], acc[i][j], 0, 0, 0);
    __builtin_amdgcn_s_setprio(0);
    bar();

    bf8v a1[4], b1[4];
#pragma unroll
    for (int i = 0; i < 4; ++i) a1[i] = *(const bf8v*)&Ab[((8 + wr * 4 + i) * 64 + lane) * 8];
#pragma unroll
    for (int j = 0; j < 4; ++j) b1[j] = *(const bf8v*)&Bb[((16 + wc * 4 + j) * 64 + lane) * 8];
    if (st) STG(s2, 1, kt2);
    if (st) vwait6(); else vwait0();
    bar();
    __builtin_amdgcn_s_setprio(1);
#pragma unroll
    for (int i = 0; i < 4; ++i)
#pragma unroll
      for (int j = 0; j < 4; ++j)
        acc[i][j] = __builtin_amdgcn_mfma_f32_16x16x32_bf16(a1[i], b1[j], acc[i][j], 0, 0, 0);
    __builtin_amdgcn_s_setprio(0);
    bar();

    const int tmp = s0; s0 = s1; s1 = s2; s2 = tmp;
  }
#undef STG

#pragma unroll
  for (int i = 0; i < 4; i++) {
    const long mrow = m0 + wr * 64 + i * 16 + quad * 4;
#pragma unroll
    for (int j = 0; j < 4; j++) {
      const long ncol = n0 + wc * 64 + j * 16 + ln;
#pragma unroll
      for (int r = 0; r < 4; r++) {
        const float fv = acc[i][j][r];
        const long m = mrow + r;
        if (mode == 0) {
          C0[m * 2048 + ncol] = f2bf(fv);
        } else if (mode == 2) {
          Cf[m * 2048 + ncol] = fv;
        } else if (mode == 1) {
          const long s = m & 2047, bb = m >> 11;
          const long hh = ncol >> 7, dc = ncol & 127;
          C0[((bb * 16 + hh) * 128 + dc) * 2048 + s] = f2bf(fv);
        } else {
          const int sec = (int)(n0 >> 11);
          const long nc = ncol & 2047;
          if (sec == 0)      C0[m * 2048 + nc] = f2bf(fv);
          else if (sec == 1) C1[m * 2048 + nc] = f2bf(fv);
          else {
            const long s = m & 2047, bb = m >> 11;
            const long hh = nc >> 7, dc = nc & 127;
            C2[((bb * 16 + hh) * 128 + dc) * 2048 + s] = f2bf(fv);
          }
        }
      }
    }
  }
}

// ---------------------------------------------------------------------------
// RoPE v2 (proven): VECTORIZED 8-wide.
// ---------------------------------------------------------------------------
__global__ __launch_bounds__(256) void rope8_k(u16* __restrict__ qb,
                                               u16* __restrict__ kb,
                                               const float* __restrict__ cs,
                                               const float* __restrict__ sn)
{
  const long idx = (long)blockIdx.x * 256 + threadIdx.x;   // [0, 1048576)
  u16* t = (idx >= 524288) ? kb : qb;
  const long i2 = idx & 524287;            // 4096 m x 16 h x 8 chunks
  const long m = i2 >> 7;
  const int rest = (int)(i2 & 127);
  const int h = rest >> 3, d0 = (rest & 7) * 8;
  const int s = (int)(m & 2047);
  const long base = m * 2048 + h * 128 + d0;
  const bf8v av = *(const bf8v*)(t + base);
  const bf8v bv = *(const bf8v*)(t + base + 64);
  const float* csp = cs + s * 128 + d0;
  const float* snp = sn + s * 128 + d0;
  const float4 c0 = *(const float4*)(csp),      c1 = *(const float4*)(csp + 4);
  const float4 c2 = *(const float4*)(csp + 64), c3 = *(const float4*)(csp + 68);
  const float4 s0 = *(const float4*)(snp),      s1 = *(const float4*)(snp + 4);
  const float4 s2 = *(const float4*)(snp + 64), s3 = *(const float4*)(snp + 68);
  const float cd[8]  = {c0.x, c0.y, c0.z, c0.w, c1.x, c1.y, c1.z, c1.w};
  const float sd[8]  = {s0.x, s0.y, s0.z, s0.w, s1.x, s1.y, s1.z, s1.w};
  const float cd2[8] = {c2.x, c2.y, c2.z, c2.w, c3.x, c3.y, c3.z, c3.w};
  const float sd2[8] = {s2.x, s2.y, s2.z, s2.w, s3.x, s3.y, s3.z, s3.w};
  bf8v o0, o1;
#pragma unroll
  for (int j = 0; j < 8; ++j) {
    const float a = bf2f((u16)av[j]), b = bf2f((u16)bv[j]);
    o0[j] = (short)f2bf(a * cd[j]  - b * sd[j]);
    o1[j] = (short)f2bf(b * cd2[j] + a * sd2[j]);
  }
  *(bf8v*)(t + base)      = o0;
  *(bf8v*)(t + base + 64) = o1;
}

// ---------------------------------------------------------------------------
// Flash attention v3 (round-6/7/9 proven, RESTORED — r12 measured v4 == v3
// with clock verified, so the simpler v3 is kept): 8 waves, QBLK=128,
// KVBLK=128, complementary q-tile pair per block, K/V dbuf, one counted
// vmcnt(8) per iter. Fixed-shift softmax; row sums via ones-MFMA.
// ---------------------------------------------------------------------------
__global__ __launch_bounds__(512) void attn_k(const u16* __restrict__ q,
                                              const u16* __restrict__ k,
                                              const u16* __restrict__ vt,
                                              u16* __restrict__ ao)
{
  __shared__ __align__(16) u16 Ks[2][16384];      // 2 x 32 KB
  __shared__ __align__(16) u16 Vs[2][16384];      // 2 x 32 KB
  __shared__ __align__(16) u16 Ps[8 * 16 * 72];   // per-wave P, stride 72 (18 KB)
  const int xa = blockIdx.x;       // 0..7
  const int bh = blockIdx.y;
  const int b = bh >> 4, h = bh & 15;
  const int tid = threadIdx.x;
  const int w = tid >> 6, lane = tid & 63;        // w: 0..7
  const int ln = lane & 15, quad = lane >> 4;

  const u16* kb0 = k + ((long)(b * 2048 + (tid & 15))) * 2048 + h * 128
                     + ((tid >> 6) & 3) * 32 + ((tid >> 4) & 3) * 8;
  const u16* vb0 = vt + ((long)(bh * 128 + (tid & 15))) * 2048
                      + ((tid >> 6) & 1) * 32 + ((tid >> 4) & 3) * 8;
  const int tb = (tid >> 7) & 1;
  const int bit8 = tid >> 8;       // 0/1
  int krow[4]; long voff[4];
#pragma unroll
  for (int it2 = 0; it2 < 4; ++it2) {
    const int ie = 2 * it2 + bit8;               // effective round 0..7
    krow[it2] = (ie >> 2) * 64 + (ie & 3) * 16;
    const int g = 2 * ie + tb;                   // 0..15
    voff[it2] = (long)((g & 7) * 16) * 2048 + (g >> 3) * 64;
  }

#define STK(sl, k0) do{                                                          \
    _Pragma("unroll")                                                            \
    for (int it2 = 0; it2 < 4; ++it2)                                            \
      async16(kb0 + (long)((k0) + krow[it2]) * 2048,                             \
              (char*)&Ks[sl][0] + it2 * 8192 + w * 1024);                        \
  }while(0)
#define STV(sl, k0) do{                                                          \
    _Pragma("unroll")                                                            \
    for (int it2 = 0; it2 < 4; ++it2)                                            \
      async16(vb0 + voff[it2] + (k0),                                            \
              (char*)&Vs[sl][0] + it2 * 8192 + w * 1024);                        \
  }while(0)

  const short one_bf = (short)0x3F80; // bf16 1.0
  const bf8v vones = {one_bf, one_bf, one_bf, one_bf, one_bf, one_bf, one_bf, one_bf};
  const float scl = 0.08838834764831845f;  // 1/sqrt(128)
  const float shift = 20.0f;
  const int wbase = w * 16 * 72;
  const int qts[2] = {15 - xa, xa};

  for (int tix = 0; tix < 2; ++tix) {
    const int qt = qts[tix];
    const int q0 = qt << 7;

    bf8v aq[4];
    {
      const u16* qp = q + ((long)(b * 2048 + q0 + w * 16 + ln)) * 2048 + h * 128;
#pragma unroll
      for (int dt = 0; dt < 4; ++dt) aq[dt] = *(const bf8v*)(qp + dt * 32 + quad * 8);
    }
    f4v O[8] = {};
    f4v Osum = {};

    STK(0, 0); STV(0, 0);

    for (int ktp = 0; ktp <= qt; ++ktp) {
      const int k0s = ktp << 7;
      const bool lastit = (ktp == qt);
      const int sl = ktp & 1;
      if (!lastit) { STK(sl ^ 1, k0s + 128); STV(sl ^ 1, k0s + 128); }
      if (!lastit) vwait8(); else vwait0();
      bar();
      const u16* Kb = &Ks[sl][0];
      const u16* Vb = &Vs[sl][0];

      f4v S[8];
#pragma unroll
      for (int jt = 0; jt < 8; jt++) {
        const int jb = (jt >> 2) * 64 + (jt & 3) * 16;
        if (lastit && jb > w * 16 + 15) {
          S[jt] = (f4v){-1e30f, -1e30f, -1e30f, -1e30f};
          continue;
        }
        const int sub = jt >> 2, jl = jt & 3;
        f4v s = {};
#pragma unroll
        for (int dt = 0; dt < 4; dt++) {
          const bf8v bk = *(const bf8v*)&Kb[(sub * 1024 + (jl * 4 + dt) * 64 + lane) * 8];
          s = __builtin_amdgcn_mfma_f32_16x16x32_bf16(aq[dt], bk, s, 0, 0, 0);
        }
        S[jt] = s;
      }
      if (lastit) {
        const int qi = w * 16 + quad * 4;
#pragma unroll
        for (int jt = 0; jt < 8; jt++) {
          const int dcol = (jt >> 2) * 64 + (jt & 3) * 16 + ln;
#pragma unroll
          for (int r = 0; r < 4; r++) {
            const float arg = (dcol > qi + r) ? -1e30f : (S[jt][r] * scl - shift);
            S[jt][r] = __expf(arg);
          }
        }
      } else {
#pragma unroll
        for (int jt = 0; jt < 8; jt++)
#pragma unroll
          for (int r = 0; r < 4; r++) S[jt][r] = __expf(S[jt][r] * scl - shift);
      }

#pragma unroll
      for (int sub = 0; sub < 2; ++sub) {
        if (sub == 1 && lastit && w < 4) break;
#pragma unroll
        for (int jl = 0; jl < 4; jl++)
#pragma unroll
          for (int r = 0; r < 4; r++)
            Ps[wbase + (quad * 4 + r) * 72 + jl * 16 + ln] = f2bf(S[sub * 4 + jl][r]);
        bf8v ap[2];
#pragma unroll
        for (int k2 = 0; k2 < 2; k2++)
          ap[k2] = *(const bf8v*)&Ps[wbase + ln * 72 + k2 * 32 + quad * 8];
#pragma unroll
        for (int nt = 0; nt < 8; nt++) {
#pragma unroll
          for (int k2 = 0; k2 < 2; k2++) {
            const bf8v bv = *(const bf8v*)&Vb[(sub * 1024 + (nt * 2 + k2) * 64 + lane) * 8];
            O[nt] = __builtin_amdgcn_mfma_f32_16x16x32_bf16(ap[k2], bv, O[nt], 0, 0, 0);
          }
        }
#pragma unroll
        for (int k2 = 0; k2 < 2; k2++)
          Osum = __builtin_amdgcn_mfma_f32_16x16x32_bf16(ap[k2], vones, Osum, 0, 0, 0);
      }
      bar();
    }

    float inv[4];
#pragma unroll
    for (int r = 0; r < 4; r++) inv[r] = 1.0f / Osum[r];
    const long ob = ((long)(b * 2048 + q0 + w * 16 + quad * 4)) * 2048 + h * 128 + ln;
#pragma unroll
    for (int r = 0; r < 4; r++)
#pragma unroll
      for (int nt = 0; nt < 8; nt++)
        ao[ob + (long)r * 2048 + nt * 16] = f2bf(O[nt][r] * inv[r]);
  }
#undef STK
#undef STV
}

// ---------------------------------------------------------------------------
extern "C" void kernel_launch(void* const* d_in, const int* in_sizes, int n_in,
                              void* d_out, int out_size, void* d_ws, size_t ws_size,
                              hipStream_t stream) {
  const float* x  = (const float*)d_in[0];
  const float* cs = (const float*)d_in[1];
  const float* sn = (const float*)d_in[2];
  const float* Wq = (const float*)d_in[3];
  const float* Wk = (const float*)d_in[4];
  const float* Wv = (const float*)d_in[5];
  const float* Wo = (const float*)d_in[6];
  float* out = (float*)d_out;

  const size_t E = 4194304;   // 2048*2048 elements
  u16* xb = (u16*)d_ws;       // [4096,2048] bf16; later aliased as aob

  const size_t need12 = 12 * E * sizeof(u16);  // 100.7 MB: up-front Wo tier
  const size_t need11 = 11 * E * sizeof(u16);  // 92.3 MB: fused path
  if (ws_size >= need12) {
    // 6 dispatches: all conversions fused, Wo converted up-front.
    u16* wqkv = xb + 2 * E;       // [6144, 2048]
    u16* qb   = wqkv + 3 * E;     // [4096, 2048]
    u16* kb   = qb + 2 * E;
    u16* vtb  = kb + 2 * E;       // [32,128,2048] V^T
    u16* wob  = vtb + 2 * E;      // [2048, 2048]
    u16* aob  = xb;

    f2ball_k<<<24576, 256, 0, stream>>>(x, Wq, Wk, Wv, Wo, xb, wqkv, wob);
    gemmq  <<<dim3(16, 16), 512, 0, stream>>>(xb, wqkv, qb, kb, vtb, nullptr, 3);
    gemm256<<<dim3(8, 32),  512, 0, stream>>>(xb, wqkv, qb, kb, vtb, nullptr, 3, 4096);
    rope8_k<<<4096, 256, 0, stream>>>(qb, kb, cs, sn);
    attn_k<<<dim3(8, 32), 512, 0, stream>>>(qb, kb, vtb, aob);
    gemm256<<<dim3(8, 32), 512, 0, stream>>>(aob, wob, nullptr, nullptr, nullptr, out, 2, 0);
  } else if (ws_size >= need11) {
    // 7 dispatches: conversions fused (no Wo region); Wo converted late.
    u16* wqkv = xb + 2 * E;       // [6144, 2048]
    u16* qb   = wqkv + 3 * E;     // [4096, 2048]
    u16* kb   = qb + 2 * E;
    u16* vtb  = kb + 2 * E;       // [32,128,2048] V^T
    u16* aob  = xb;

    f2ball_k<<<20480, 256, 0, stream>>>(x, Wq, Wk, Wv, Wo, xb, wqkv, wqkv /*unused*/);
    gemmq  <<<dim3(16, 16), 512, 0, stream>>>(xb, wqkv, qb, kb, vtb, nullptr, 3);
    gemm256<<<dim3(8, 32),  512, 0, stream>>>(xb, wqkv, qb, kb, vtb, nullptr, 3, 4096);
    rope8_k<<<4096, 256, 0, stream>>>(qb, kb, cs, sn);
    attn_k<<<dim3(8, 32), 512, 0, stream>>>(qb, kb, vtb, aob);
    f2b_k<<<4096, 256, 0, stream>>>(Wo, wqkv);
    gemm256<<<dim3(8, 32), 512, 0, stream>>>(aob, wqkv, nullptr, nullptr, nullptr, out, 2, 0);
  } else {
    // fallback: per-weight conversion, 75.6 MB (known to fit)
    u16* wb  = xb + 2 * E;        // [2048,2048], reused per-W
    u16* qb  = wb + E;
    u16* kb  = qb + 2 * E;
    u16* vtb = kb + 2 * E;
    u16* aob = xb;

    f2b_k<<<8192, 256, 0, stream>>>(x, xb);
    f2b_k<<<4096, 256, 0, stream>>>(Wq, wb);
    gemm256<<<dim3(8, 32), 512, 0, stream>>>(xb, wb, qb, nullptr, nullptr, nullptr, 0, 0);
    f2b_k<<<4096, 256, 0, stream>>>(Wk, wb);
    gemm256<<<dim3(8, 32), 512, 0, stream>>>(xb, wb, kb, nullptr, nullptr, nullptr, 0, 0);
    f2b_k<<<4096, 256, 0, stream>>>(Wv, wb);
    gemm256<<<dim3(8, 32), 512, 0, stream>>>(xb, wb, vtb, nullptr, nullptr, nullptr, 1, 0);
    rope8_k<<<4096, 256, 0, stream>>>(qb, kb, cs, sn);
    attn_k<<<dim3(8, 32), 512, 0, stream>>>(qb, kb, vtb, aob);
    f2b_k<<<4096, 256, 0, stream>>>(Wo, wb);
    gemm256<<<dim3(8, 32), 512, 0, stream>>>(aob, wb, nullptr, nullptr, nullptr, out, 2, 0);
  }
}

// Round 14
// 443.950 us; speedup vs baseline: 1.3707x; 1.3707x over previous
//
#include <hip/hip_runtime.h>

typedef unsigned short u16;
typedef __attribute__((ext_vector_type(8))) short bf8v;   // 8 bf16 = 4 VGPRs
typedef __attribute__((ext_vector_type(4))) float f4v;

#define DEV static __device__ __forceinline__

DEV float bf2f(u16 u){ unsigned x = ((unsigned)u) << 16; float f; __builtin_memcpy(&f, &x, 4); return f; }
DEV u16 f2bf(float f){ unsigned x; __builtin_memcpy(&x, &f, 4); x += 0x7fff + ((x >> 16) & 1); return (u16)(x >> 16); }

DEV void async16(const void* g, void* l){
  __builtin_amdgcn_global_load_lds((const __attribute__((address_space(1))) unsigned*)g,
                                   (__attribute__((address_space(3))) unsigned*)l, 16, 0, 0);
}

DEV void vwait8(){ asm volatile("s_waitcnt vmcnt(8)" ::: "memory"); }
DEV void vwait6(){ asm volatile("s_waitcnt vmcnt(6)" ::: "memory"); }
DEV void vwait0(){ asm volatile("s_waitcnt vmcnt(0)" ::: "memory"); }
DEV void vw(int n){
  switch(n){
    case 8: asm volatile("s_waitcnt vmcnt(8)" ::: "memory"); break;
    case 4: asm volatile("s_waitcnt vmcnt(4)" ::: "memory"); break;
    case 2: asm volatile("s_waitcnt vmcnt(2)" ::: "memory"); break;
    default: asm volatile("s_waitcnt vmcnt(0)" ::: "memory"); break;
  }
}
DEV void bar(){ asm volatile("s_barrier" ::: "memory"); }

// ---------------------------------------------------------------------------
// fp32 -> bf16 conversion, 4 elements/thread (kept for tier-2 / fallback).
// ---------------------------------------------------------------------------
__global__ __launch_bounds__(256) void f2b_k(const float* __restrict__ src,
                                             u16* __restrict__ dst)
{
  const long i = ((long)blockIdx.x * 256 + threadIdx.x) * 4;
  const float4 v = *(const float4*)(src + i);
  ushort4 o;
  o.x = f2bf(v.x); o.y = f2bf(v.y); o.z = f2bf(v.z); o.w = f2bf(v.w);
  *(ushort4*)(dst + i) = o;
}

// ---------------------------------------------------------------------------
// f2ball_k: ALL fp32->bf16 conversions in ONE dispatch (boundary reduction).
// Sections by blockIdx.x:
//   [0,8192)      x  -> xb      (2E elems)
//   [8192,20480)  Wq/Wk/Wv -> wqkv [6144,2048]
//   [20480,24576) Wo -> wob     (only reached when grid=24576, ws>=12E tier)
// Math identical to old f2b/f2b3 -> bit-identical outputs.
// ---------------------------------------------------------------------------
__global__ __launch_bounds__(256) void f2ball_k(const float* __restrict__ x,
                                                const float* __restrict__ wq,
                                                const float* __restrict__ wk,
                                                const float* __restrict__ wv,
                                                const float* __restrict__ wo,
                                                u16* __restrict__ xb,
                                                u16* __restrict__ wqkv,
                                                u16* __restrict__ wob)
{
  const int bx = blockIdx.x;
  const int tid = threadIdx.x;
  const float* s;
  u16* d;
  long soff, doff;
  if (bx < 8192) {
    s = x; d = xb;
    soff = doff = (long)bx * 1024 + tid * 4;
  } else if (bx < 20480) {
    const int b2 = bx - 8192;                    // 0..12287
    s = b2 < 4096 ? wq : (b2 < 8192 ? wk : wv);
    d = wqkv;
    soff = (long)(b2 & 4095) * 1024 + tid * 4;
    doff = (long)b2 * 1024 + tid * 4;
  } else {
    const int b3 = bx - 20480;                   // 0..4095
    s = wo; d = wob;
    soff = doff = (long)b3 * 1024 + tid * 4;
  }
  const float4 v = *(const float4*)(s + soff);
  ushort4 o;
  o.x = f2bf(v.x); o.y = f2bf(v.y); o.z = f2bf(v.z); o.w = f2bf(v.w);
  *(ushort4*)(d + doff) = o;
}

// ---------------------------------------------------------------------------
// gemmq (round-7/9/12 proven, FROZEN): 256x256 tile, BK=64, 8 waves, dbuf
// 128 KB, fine ring, counted vmcnt per phase. 96 us @ 256-block grids,
// MfmaUtil ~28%. Clock tripwire: ~190us => degraded-clock session (fired
// rounds 8 and 13; those results are discarded).
// ---------------------------------------------------------------------------
constexpr int KDIM = 2048;

__global__ __launch_bounds__(512, 2) void gemmq(const u16* __restrict__ A,
                                                const u16* __restrict__ B,
                                                u16* __restrict__ C0,
                                                u16* __restrict__ C1,
                                                u16* __restrict__ C2,
                                                float* __restrict__ Cf, int mode)
{
  __shared__ __align__(16) u16 Asm[2][16384];   // 64 KB
  __shared__ __align__(16) u16 Bsm[2][16384];   // 64 KB

  const int tid = threadIdx.x;
  const int w = tid >> 6, lane = tid & 63;
  const int ln = lane & 15, quad = lane >> 4;
  const int wr = w >> 2, wc = w & 3;           // 2 x 4 wave grid

  const int gx = gridDim.x;
  const int nwg = gx * gridDim.y;
  const int wg = blockIdx.y * gx + blockIdx.x;
  const int swz = (wg & 7) * (nwg >> 3) + (wg >> 3);
  const int bx = swz % gx, by = swz / gx;
  const long m0 = (long)by << 8, n0 = (long)bx << 8;

  f4v acc[8][4] = {};

  const int q = w >> 1;                        // 0..3
  const int colb = (w & 1) * 32 + quad * 8;    // k elems within BK
  long gArow[4], gBrow[4];
  {
    const int Ab4[4] = {0, 8, 4, 12};
    const int Bb4[4] = {0, 8, 2, 10};
#pragma unroll
    for (int r = 0; r < 4; ++r) {
      gArow[r] = (long)((Ab4[r] + q) * 16 + ln) * KDIM;
      gBrow[r] = (long)((Bb4[r] + (q & 1) + (q >> 1) * 4) * 16 + ln) * KDIM;
    }
  }
  const u16* gA = A + m0 * KDIM + colb;
  const u16* gB = B + n0 * KDIM + colb;

#define STAGE_A(sl, r, kt) async16(gA + gArow[r] + (kt), (char*)Asm + (sl)*32768 + (r)*8192 + w*1024)
#define STAGE_B(sl, r, kt) async16(gB + gBrow[r] + (kt), (char*)Bsm + (sl)*32768 + (r)*8192 + w*1024)

  STAGE_A(0,0,0);  STAGE_A(0,1,0);    // Al_0
  STAGE_B(0,0,0);  STAGE_B(0,1,0);    // Bl_0
  STAGE_B(0,2,0);  STAGE_B(0,3,0);    // Bh_0
  STAGE_A(0,2,0);  STAGE_A(0,3,0);    // Ah_0
  STAGE_A(1,0,64); STAGE_A(1,1,64);   // Al_1
  STAGE_B(1,0,64); STAGE_B(1,1,64);   // Bl_1
  vwait8();
  bar();

  const int nt = KDIM / 64;   // 32
  for (int t = 0; t < nt; ++t) {
    const int cs = t & 1;
    const u16* Ab = Asm[cs];
    const u16* Bb = Bsm[cs];
    int w1 = 8, w2 = 8, w3 = 8, w4 = 8;
    if (t == nt - 2) { w4 = 4; }
    else if (t == nt - 1) { w1 = 2; w2 = 0; w3 = 0; w4 = 0; }
    const long kn1 = (long)(t + 1) * 64;
    const long kn2 = (long)(t + 2) * 64;

    bf8v aL[4][2], aH[4][2], bL[2][2], bH[2][2];

    // ---- phase 1 ----
#pragma unroll
    for (int i = 0; i < 4; ++i) {
      const int ib = (i + wr * 4) * 2;
      aL[i][0] = *(const bf8v*)&Ab[((ib + 0) * 64 + lane) * 8];
      aL[i][1] = *(const bf8v*)&Ab[((ib + 1) * 64 + lane) * 8];
    }
#pragma unroll
    for (int j = 0; j < 2; ++j) {
      const int jb = (j + wc * 2) * 2;
      bL[j][0] = *(const bf8v*)&Bb[((jb + 0) * 64 + lane) * 8];
      bL[j][1] = *(const bf8v*)&Bb[((jb + 1) * 64 + lane) * 8];
    }
    if (t + 1 < nt) { STAGE_B(cs ^ 1, 2, kn1); STAGE_B(cs ^ 1, 3, kn1); }
    vw(w1); bar();
    __builtin_amdgcn_s_setprio(1);
#pragma unroll
    for (int i = 0; i < 4; ++i)
#pragma unroll
      for (int j = 0; j < 2; ++j) {
        acc[i][j] = __builtin_amdgcn_mfma_f32_16x16x32_bf16(aL[i][0], bL[j][0], acc[i][j], 0, 0, 0);
        acc[i][j] = __builtin_amdgcn_mfma_f32_16x16x32_bf16(aL[i][1], bL[j][1], acc[i][j], 0, 0, 0);
      }
    __builtin_amdgcn_s_setprio(0);

    // ---- phase 2 ----
#pragma unroll
    for (int j = 0; j < 2; ++j) {
      const int jb = ((j & 1) + 8 + wc * 2) * 2;
      bH[j][0] = *(const bf8v*)&Bb[((jb + 0) * 64 + lane) * 8];
      bH[j][1] = *(const bf8v*)&Bb[((jb + 1) * 64 + lane) * 8];
    }
    if (t + 1 < nt) { STAGE_A(cs ^ 1, 2, kn1); STAGE_A(cs ^ 1, 3, kn1); }
    vw(w2); bar();
    __builtin_amdgcn_s_setprio(1);
#pragma unroll
    for (int i = 0; i < 4; ++i)
#pragma unroll
      for (int j = 0; j < 2; ++j) {
        acc[i][2 + j] = __builtin_amdgcn_mfma_f32_16x16x32_bf16(aL[i][0], bH[j][0], acc[i][2 + j], 0, 0, 0);
        acc[i][2 + j] = __builtin_amdgcn_mfma_f32_16x16x32_bf16(aL[i][1], bH[j][1], acc[i][2 + j], 0, 0, 0);
      }
    __builtin_amdgcn_s_setprio(0);

    // ---- phase 3 ----
#pragma unroll
    for (int i = 0; i < 4; ++i) {
      const int ib = (i + 8 + wr * 4) * 2;
      aH[i][0] = *(const bf8v*)&Ab[((ib + 0) * 64 + lane) * 8];
      aH[i][1] = *(const bf8v*)&Ab[((ib + 1) * 64 + lane) * 8];
    }
    if (t + 2 < nt) { STAGE_A(cs, 0, kn2); STAGE_A(cs, 1, kn2); }
    vw(w3); bar();
    __builtin_amdgcn_s_setprio(1);
#pragma unroll
    for (int i = 0; i < 4; ++i)
#pragma unroll
      for (int j = 0; j < 2; ++j) {
        acc[4 + i][j] = __builtin_amdgcn_mfma_f32_16x16x32_bf16(aH[i][0], bL[j][0], acc[4 + i][j], 0, 0, 0);
        acc[4 + i][j] = __builtin_amdgcn_mfma_f32_16x16x32_bf16(aH[i][1], bL[j][1], acc[4 + i][j], 0, 0, 0);
      }
    __builtin_amdgcn_s_setprio(0);

    // ---- phase 4 ----
    if (t + 2 < nt) { STAGE_B(cs, 0, kn2); STAGE_B(cs, 1, kn2); }
    vw(w4); bar();
    __builtin_amdgcn_s_setprio(1);
#pragma unroll
    for (int i = 0; i < 4; ++i)
#pragma unroll
      for (int j = 0; j < 2; ++j) {
        acc[4 + i][2 + j] = __builtin_amdgcn_mfma_f32_16x16x32_bf16(aH[i][0], bH[j][0], acc[4 + i][2 + j], 0, 0, 0);
        acc[4 + i][2 + j] = __builtin_amdgcn_mfma_f32_16x16x32_bf16(aH[i][1], bH[j][1], acc[4 + i][2 + j], 0, 0, 0);
      }
    __builtin_amdgcn_s_setprio(0);
  }
#undef STAGE_A
#undef STAGE_B

#pragma unroll
  for (int i = 0; i < 8; i++) {
    const long mrow = m0 + wr * 128 + i * 16 + quad * 4;
#pragma unroll
    for (int j = 0; j < 4; j++) {
      const long ncol = n0 + wc * 64 + j * 16 + ln;
#pragma unroll
      for (int r = 0; r < 4; r++) {
        const float fv = acc[i][j][r];
        const long m = mrow + r;
        if (mode == 0) {
          C0[m * 2048 + ncol] = f2bf(fv);
        } else if (mode == 2) {
          Cf[m * 2048 + ncol] = fv;
        } else if (mode == 1) {
          const long s = m & 2047, bb = m >> 11;
          const long hh = ncol >> 7, dc = ncol & 127;
          C0[((bb * 16 + hh) * 128 + dc) * 2048 + s] = f2bf(fv);
        } else {
          const int sec = (int)(n0 >> 11);
          const long nc = ncol & 2047;
          if (sec == 0)      C0[m * 2048 + nc] = f2bf(fv);
          else if (sec == 1) C1[m * 2048 + nc] = f2bf(fv);
          else {
            const long s = m & 2047, bb = m >> 11;
            const long hh = nc >> 7, dc = nc & 127;
            C2[((bb * 16 + hh) * 128 + dc) * 2048 + s] = f2bf(fv);
          }
        }
      }
    }
  }
}

// ---------------------------------------------------------------------------
// GEMM v5 (round-4 proven, UNCHANGED): 128x256 tile, 3-slot ring, fine
// interleave, one counted vmcnt(6)/tile. nofs = N-column offset.
// ---------------------------------------------------------------------------
__global__ __launch_bounds__(512, 2) void gemm256(const u16* __restrict__ A,
                                                  const u16* __restrict__ B,
                                                  u16* __restrict__ C0,
                                                  u16* __restrict__ C1,
                                                  u16* __restrict__ C2,
                                                  float* __restrict__ Cf, int mode,
                                                  int nofs)
{
  __shared__ __align__(16) u16 Asm[3][8192];    // 3 x 16 KB
  __shared__ __align__(16) u16 Bsm[3][16384];   // 3 x 32 KB

  const int tid = threadIdx.x;
  const int w = tid >> 6, lane = tid & 63;
  const int ln = lane & 15, quad = lane >> 4;
  const int wr = w >> 2, wc = w & 3;

  const int gx = gridDim.x;
  const int nwg = gx * gridDim.y;
  const int wg = blockIdx.y * gx + blockIdx.x;
  const int swz = (wg & 7) * (nwg >> 3) + (wg >> 3);
  const int bx = swz % gx, by = swz / gx;
  const long m0 = (long)by << 7, n0 = ((long)bx << 8) + nofs;

  f4v acc[4][4] = {};

  const u16* pA  = A + (m0 + w * 16 + ln) * (long)KDIM + quad * 8;
  const u16* pB0 = B + (n0 + w * 16 + ln) * (long)KDIM + quad * 8;
  const u16* pB1 = B + (n0 + (8 + w) * 16 + ln) * (long)KDIM + quad * 8;
  char* ldsA = (char*)Asm + (long)tid * 16;
  char* ldsB = (char*)Bsm + (long)tid * 16;

#define STG(sl, ks, kt) do{                                                     \
    async16(pA  + (kt) + (ks) * 32, ldsA + (sl) * 16384 + (ks) * 8192);         \
    async16(pB0 + (kt) + (ks) * 32, ldsB + (sl) * 32768 + (ks) * 16384);        \
    async16(pB1 + (kt) + (ks) * 32, ldsB + (sl) * 32768 + (ks) * 16384 + 8192); \
  }while(0)

  STG(0, 0, 0);  STG(0, 1, 0);
  STG(1, 0, 64); STG(1, 1, 64);
  vwait6();
  bar();

  int s0 = 0, s1 = 1, s2 = 2;
  const int nt = KDIM / 64;           // 32
  for (int t = 0; t < nt; ++t) {
    const u16* Ab = Asm[s0];
    const u16* Bb = Bsm[s0];
    const bool st = (t + 2 < nt);
    const long kt2 = (long)(t + 2) * 64;

    bf8v a0[4], b0[4];
#pragma unroll
    for (int i = 0; i < 4; ++i) a0[i] = *(const bf8v*)&Ab[((wr * 4 + i) * 64 + lane) * 8];
#pragma unroll
    for (int j = 0; j < 4; ++j) b0[j] = *(const bf8v*)&Bb[((wc * 4 + j) * 64 + lane) * 8];
    if (st) STG(s2, 0, kt2);
    bar();
    __builtin_amdgcn_s_setprio(1);
#pragma unroll
    for (int i = 0; i < 4; ++i)
#pragma unroll
      for (int j = 0; j < 4; ++j)
        acc[i][j] = __builtin_amdgcn_mfma_f32_16x16x32_bf16(a0[i], b0[j], acc[i][j], 0, 0, 0);
    __builtin_amdgcn_s_setprio(0);
    bar();

    bf8v a1[4], b1[4];
#pragma unroll
    for (int i = 0; i < 4; ++i) a1[i] = *(const bf8v*)&Ab[((8 + wr * 4 + i) * 64 + lane) * 8];
#pragma unroll
    for (int j = 0; j < 4; ++j) b1[j] = *(const bf8v*)&Bb[((16 + wc * 4 + j) * 64 + lane) * 8];
    if (st) STG(s2, 1, kt2);
    if (st) vwait6(); else vwait0();
    bar();
    __builtin_amdgcn_s_setprio(1);
#pragma unroll
    for (int i = 0; i < 4; ++i)
#pragma unroll
      for (int j = 0; j < 4; ++j)
        acc[i][j] = __builtin_amdgcn_mfma_f32_16x16x32_bf16(a1[i], b1[j], acc[i][j], 0, 0, 0);
    __builtin_amdgcn_s_setprio(0);
    bar();

    const int tmp = s0; s0 = s1; s1 = s2; s2 = tmp;
  }
#undef STG

#pragma unroll
  for (int i = 0; i < 4; i++) {
    const long mrow = m0 + wr * 64 + i * 16 + quad * 4;
#pragma unroll
    for (int j = 0; j < 4; j++) {
      const long ncol = n0 + wc * 64 + j * 16 + ln;
#pragma unroll
      for (int r = 0; r < 4; r++) {
        const float fv = acc[i][j][r];
        const long m = mrow + r;
        if (mode == 0) {
          C0[m * 2048 + ncol] = f2bf(fv);
        } else if (mode == 2) {
          Cf[m * 2048 + ncol] = fv;
        } else if (mode == 1) {
          const long s = m & 2047, bb = m >> 11;
          const long hh = ncol >> 7, dc = ncol & 127;
          C0[((bb * 16 + hh) * 128 + dc) * 2048 + s] = f2bf(fv);
        } else {
          const int sec = (int)(n0 >> 11);
          const long nc = ncol & 2047;
          if (sec == 0)      C0[m * 2048 + nc] = f2bf(fv);
          else if (sec == 1) C1[m * 2048 + nc] = f2bf(fv);
          else {
            const long s = m & 2047, bb = m >> 11;
            const long hh = nc >> 7, dc = nc & 127;
            C2[((bb * 16 + hh) * 128 + dc) * 2048 + s] = f2bf(fv);
          }
        }
      }
    }
  }
}

// ---------------------------------------------------------------------------
// RoPE v2 (proven): VECTORIZED 8-wide.
// ---------------------------------------------------------------------------
__global__ __launch_bounds__(256) void rope8_k(u16* __restrict__ qb,
                                               u16* __restrict__ kb,
                                               const float* __restrict__ cs,
                                               const float* __restrict__ sn)
{
  const long idx = (long)blockIdx.x * 256 + threadIdx.x;   // [0, 1048576)
  u16* t = (idx >= 524288) ? kb : qb;
  const long i2 = idx & 524287;            // 4096 m x 16 h x 8 chunks
  const long m = i2 >> 7;
  const int rest = (int)(i2 & 127);
  const int h = rest >> 3, d0 = (rest & 7) * 8;
  const int s = (int)(m & 2047);
  const long base = m * 2048 + h * 128 + d0;
  const bf8v av = *(const bf8v*)(t + base);
  const bf8v bv = *(const bf8v*)(t + base + 64);
  const float* csp = cs + s * 128 + d0;
  const float* snp = sn + s * 128 + d0;
  const float4 c0 = *(const float4*)(csp),      c1 = *(const float4*)(csp + 4);
  const float4 c2 = *(const float4*)(csp + 64), c3 = *(const float4*)(csp + 68);
  const float4 s0 = *(const float4*)(snp),      s1 = *(const float4*)(snp + 4);
  const float4 s2 = *(const float4*)(snp + 64), s3 = *(const float4*)(snp + 68);
  const float cd[8]  = {c0.x, c0.y, c0.z, c0.w, c1.x, c1.y, c1.z, c1.w};
  const float sd[8]  = {s0.x, s0.y, s0.z, s0.w, s1.x, s1.y, s1.z, s1.w};
  const float cd2[8] = {c2.x, c2.y, c2.z, c2.w, c3.x, c3.y, c3.z, c3.w};
  const float sd2[8] = {s2.x, s2.y, s2.z, s2.w, s3.x, s3.y, s3.z, s3.w};
  bf8v o0, o1;
#pragma unroll
  for (int j = 0; j < 8; ++j) {
    const float a = bf2f((u16)av[j]), b = bf2f((u16)bv[j]);
    o0[j] = (short)f2bf(a * cd[j]  - b * sd[j]);
    o1[j] = (short)f2bf(b * cd2[j] + a * sd2[j]);
  }
  *(bf8v*)(t + base)      = o0;
  *(bf8v*)(t + base + 64) = o1;
}

// ---------------------------------------------------------------------------
// Flash attention v3 (round-6/7/9 proven): 8 waves, QBLK=128, KVBLK=128,
// complementary q-tile pair per block, K/V dbuf, one counted vmcnt(8) per
// iter. Fixed-shift softmax; row sums via ones-MFMA.
// ---------------------------------------------------------------------------
__global__ __launch_bounds__(512) void attn_k(const u16* __restrict__ q,
                                              const u16* __restrict__ k,
                                              const u16* __restrict__ vt,
                                              u16* __restrict__ ao)
{
  __shared__ __align__(16) u16 Ks[2][16384];      // 2 x 32 KB
  __shared__ __align__(16) u16 Vs[2][16384];      // 2 x 32 KB
  __shared__ __align__(16) u16 Ps[8 * 16 * 72];   // per-wave P, stride 72 (18 KB)
  const int xa = blockIdx.x;       // 0..7
  const int bh = blockIdx.y;
  const int b = bh >> 4, h = bh & 15;
  const int tid = threadIdx.x;
  const int w = tid >> 6, lane = tid & 63;        // w: 0..7
  const int ln = lane & 15, quad = lane >> 4;

  const u16* kb0 = k + ((long)(b * 2048 + (tid & 15))) * 2048 + h * 128
                     + ((tid >> 6) & 3) * 32 + ((tid >> 4) & 3) * 8;
  const u16* vb0 = vt + ((long)(bh * 128 + (tid & 15))) * 2048
                      + ((tid >> 6) & 1) * 32 + ((tid >> 4) & 3) * 8;
  const int tb = (tid >> 7) & 1;
  const int bit8 = tid >> 8;       // 0/1
  int krow[4]; long voff[4];
#pragma unroll
  for (int it2 = 0; it2 < 4; ++it2) {
    const int ie = 2 * it2 + bit8;               // effective round 0..7
    krow[it2] = (ie >> 2) * 64 + (ie & 3) * 16;
    const int g = 2 * ie + tb;                   // 0..15
    voff[it2] = (long)((g & 7) * 16) * 2048 + (g >> 3) * 64;
  }

#define STK(sl, k0) do{                                                          \
    _Pragma("unroll")                                                            \
    for (int it2 = 0; it2 < 4; ++it2)                                            \
      async16(kb0 + (long)((k0) + krow[it2]) * 2048,                             \
              (char*)&Ks[sl][0] + it2 * 8192 + w * 1024);                        \
  }while(0)
#define STV(sl, k0) do{                                                          \
    _Pragma("unroll")                                                            \
    for (int it2 = 0; it2 < 4; ++it2)                                            \
      async16(vb0 + voff[it2] + (k0),                                            \
              (char*)&Vs[sl][0] + it2 * 8192 + w * 1024);                        \
  }while(0)

  const short one_bf = (short)0x3F80; // bf16 1.0
  const bf8v vones = {one_bf, one_bf, one_bf, one_bf, one_bf, one_bf, one_bf, one_bf};
  const float scl = 0.08838834764831845f;  // 1/sqrt(128)
  const float shift = 20.0f;
  const int wbase = w * 16 * 72;
  const int qts[2] = {15 - xa, xa};

  for (int tix = 0; tix < 2; ++tix) {
    const int qt = qts[tix];
    const int q0 = qt << 7;

    bf8v aq[4];
    {
      const u16* qp = q + ((long)(b * 2048 + q0 + w * 16 + ln)) * 2048 + h * 128;
#pragma unroll
      for (int dt = 0; dt < 4; ++dt) aq[dt] = *(const bf8v*)(qp + dt * 32 + quad * 8);
    }
    f4v O[8] = {};
    f4v Osum = {};

    STK(0, 0); STV(0, 0);

    for (int ktp = 0; ktp <= qt; ++ktp) {
      const int k0s = ktp << 7;
      const bool lastit = (ktp == qt);
      const int sl = ktp & 1;
      if (!lastit) { STK(sl ^ 1, k0s + 128); STV(sl ^ 1, k0s + 128); }
      if (!lastit) vwait8(); else vwait0();
      bar();
      const u16* Kb = &Ks[sl][0];
      const u16* Vb = &Vs[sl][0];

      f4v S[8];
#pragma unroll
      for (int jt = 0; jt < 8; jt++) {
        const int jb = (jt >> 2) * 64 + (jt & 3) * 16;
        if (lastit && jb > w * 16 + 15) {
          S[jt] = (f4v){-1e30f, -1e30f, -1e30f, -1e30f};
          continue;
        }
        const int sub = jt >> 2, jl = jt & 3;
        f4v s = {};
#pragma unroll
        for (int dt = 0; dt < 4; dt++) {
          const bf8v bk = *(const bf8v*)&Kb[(sub * 1024 + (jl * 4 + dt) * 64 + lane) * 8];
          s = __builtin_amdgcn_mfma_f32_16x16x32_bf16(aq[dt], bk, s, 0, 0, 0);
        }
        S[jt] = s;
      }
      if (lastit) {
        const int qi = w * 16 + quad * 4;
#pragma unroll
        for (int jt = 0; jt < 8; jt++) {
          const int dcol = (jt >> 2) * 64 + (jt & 3) * 16 + ln;
#pragma unroll
          for (int r = 0; r < 4; r++) {
            const float arg = (dcol > qi + r) ? -1e30f : (S[jt][r] * scl - shift);
            S[jt][r] = __expf(arg);
          }
        }
      } else {
#pragma unroll
        for (int jt = 0; jt < 8; jt++)
#pragma unroll
          for (int r = 0; r < 4; r++) S[jt][r] = __expf(S[jt][r] * scl - shift);
      }

#pragma unroll
      for (int sub = 0; sub < 2; ++sub) {
        if (sub == 1 && lastit && w < 4) break;
#pragma unroll
        for (int jl = 0; jl < 4; jl++)
#pragma unroll
          for (int r = 0; r < 4; r++)
            Ps[wbase + (quad * 4 + r) * 72 + jl * 16 + ln] = f2bf(S[sub * 4 + jl][r]);
        bf8v ap[2];
#pragma unroll
        for (int k2 = 0; k2 < 2; k2++)
          ap[k2] = *(const bf8v*)&Ps[wbase + ln * 72 + k2 * 32 + quad * 8];
#pragma unroll
        for (int nt = 0; nt < 8; nt++) {
#pragma unroll
          for (int k2 = 0; k2 < 2; k2++) {
            const bf8v bv = *(const bf8v*)&Vb[(sub * 1024 + (nt * 2 + k2) * 64 + lane) * 8];
            O[nt] = __builtin_amdgcn_mfma_f32_16x16x32_bf16(ap[k2], bv, O[nt], 0, 0, 0);
          }
        }
#pragma unroll
        for (int k2 = 0; k2 < 2; k2++)
          Osum = __builtin_amdgcn_mfma_f32_16x16x32_bf16(ap[k2], vones, Osum, 0, 0, 0);
      }
      bar();
    }

    float inv[4];
#pragma unroll
    for (int r = 0; r < 4; r++) inv[r] = 1.0f / Osum[r];
    const long ob = ((long)(b * 2048 + q0 + w * 16 + quad * 4)) * 2048 + h * 128 + ln;
#pragma unroll
    for (int r = 0; r < 4; r++)
#pragma unroll
      for (int nt = 0; nt < 8; nt++)
        ao[ob + (long)r * 2048 + nt * 16] = f2bf(O[nt][r] * inv[r]);
  }
#undef STK
#undef STV
}

// ---------------------------------------------------------------------------
extern "C" void kernel_launch(void* const* d_in, const int* in_sizes, int n_in,
                              void* d_out, int out_size, void* d_ws, size_t ws_size,
                              hipStream_t stream) {
  const float* x  = (const float*)d_in[0];
  const float* cs = (const float*)d_in[1];
  const float* sn = (const float*)d_in[2];
  const float* Wq = (const float*)d_in[3];
  const float* Wk = (const float*)d_in[4];
  const float* Wv = (const float*)d_in[5];
  const float* Wo = (const float*)d_in[6];
  float* out = (float*)d_out;

  const size_t E = 4194304;   // 2048*2048 elements
  u16* xb = (u16*)d_ws;       // [4096,2048] bf16; later aliased as aob

  const size_t need12 = 12 * E * sizeof(u16);  // 100.7 MB: up-front Wo tier
  const size_t need11 = 11 * E * sizeof(u16);  // 92.3 MB: fused path
  if (ws_size >= need12) {
    // 6 dispatches: all conversions fused, Wo converted up-front.
    u16* wqkv = xb + 2 * E;       // [6144, 2048]
    u16* qb   = wqkv + 3 * E;     // [4096, 2048]
    u16* kb   = qb + 2 * E;
    u16* vtb  = kb + 2 * E;       // [32,128,2048] V^T
    u16* wob  = vtb + 2 * E;      // [2048, 2048]
    u16* aob  = xb;

    f2ball_k<<<24576, 256, 0, stream>>>(x, Wq, Wk, Wv, Wo, xb, wqkv, wob);
    gemmq  <<<dim3(16, 16), 512, 0, stream>>>(xb, wqkv, qb, kb, vtb, nullptr, 3);
    gemm256<<<dim3(8, 32),  512, 0, stream>>>(xb, wqkv, qb, kb, vtb, nullptr, 3, 4096);
    rope8_k<<<4096, 256, 0, stream>>>(qb, kb, cs, sn);
    attn_k<<<dim3(8, 32), 512, 0, stream>>>(qb, kb, vtb, aob);
    gemm256<<<dim3(8, 32), 512, 0, stream>>>(aob, wob, nullptr, nullptr, nullptr, out, 2, 0);
  } else if (ws_size >= need11) {
    // 7 dispatches: conversions fused (no Wo region); Wo converted late.
    u16* wqkv = xb + 2 * E;       // [6144, 2048]
    u16* qb   = wqkv + 3 * E;     // [4096, 2048]
    u16* kb   = qb + 2 * E;
    u16* vtb  = kb + 2 * E;       // [32,128,2048] V^T
    u16* aob  = xb;

    f2ball_k<<<20480, 256, 0, stream>>>(x, Wq, Wk, Wv, Wo, xb, wqkv, wqkv /*unused*/);
    gemmq  <<<dim3(16, 16), 512, 0, stream>>>(xb, wqkv, qb, kb, vtb, nullptr, 3);
    gemm256<<<dim3(8, 32),  512, 0, stream>>>(xb, wqkv, qb, kb, vtb, nullptr, 3, 4096);
    rope8_k<<<4096, 256, 0, stream>>>(qb, kb, cs, sn);
    attn_k<<<dim3(8, 32), 512, 0, stream>>>(qb, kb, vtb, aob);
    f2b_k<<<4096, 256, 0, stream>>>(Wo, wqkv);
    gemm256<<<dim3(8, 32), 512, 0, stream>>>(aob, wqkv, nullptr, nullptr, nullptr, out, 2, 0);
  } else {
    // fallback: per-weight conversion, 75.6 MB (known to fit)
    u16* wb  = xb + 2 * E;        // [2048,2048], reused per-W
    u16* qb  = wb + E;
    u16* kb  = qb + 2 * E;
    u16* vtb = kb + 2 * E;
    u16* aob = xb;

    f2b_k<<<8192, 256, 0, stream>>>(x, xb);
    f2b_k<<<4096, 256, 0, stream>>>(Wq, wb);
    gemm256<<<dim3(8, 32), 512, 0, stream>>>(xb, wb, qb, nullptr, nullptr, nullptr, 0, 0);
    f2b_k<<<4096, 256, 0, stream>>>(Wk, wb);
    gemm256<<<dim3(8, 32), 512, 0, stream>>>(xb, wb, kb, nullptr, nullptr, nullptr, 0, 0);
    f2b_k<<<4096, 256, 0, stream>>>(Wv, wb);
    gemm256<<<dim3(8, 32), 512, 0, stream>>>(xb, wb, vtb, nullptr, nullptr, nullptr, 1, 0);
    rope8_k<<<4096, 256, 0, stream>>>(qb, kb, cs, sn);
    attn_k<<<dim3(8, 32), 512, 0, stream>>>(qb, kb, vtb, aob);
    f2b_k<<<4096, 256, 0, stream>>>(Wo, wb);
    gemm256<<<dim3(8, 32), 512, 0, stream>>>(aob, wb, nullptr, nullptr, nullptr, out, 2, 0);
  }
}